// Round 2
// baseline (3081.348 us; speedup 1.0000x reference)
//
#include <hip/hip_runtime.h>
#include <math.h>

#define BN 4
#define HN 96
#define WN 312
#define CN 384
#define D1 49
#define HW (HN*WN)          // 29952
#define NPIX (BN*HW)        // 119808 = 468*256
#define CVSZ (BN*D1*HW)

// ---------------- cost volume kernel ----------------
// cost[d,h,x] = dot(featL[h,x,:], featR[h,x-d,:]) for x>=d else -inf
// Tile: 128 x per block, all 52 d (4 groups of 13). 128 threads:
// xh = t&31 (owns x = 4*xh+i, i<4), dg = t>>5 (owns d = 13*dg+j, j<13).
// LDS staged in KC=32 channel chunks, stored as float4 with quad swizzle
// quad' = (q + (row>>2)) & 7  -> 16B-aligned ds_*_b128, conflict-free for
// lane-row-stride-4 access patterns (8 lanes cover all 32 banks).
#define TX 128
#define RR (TX+48)   // 176 R rows
#define KC 32        // 8 float4 quads per row

__device__ __forceinline__ int swz(int row, int q) {
    return row * 8 + ((q + (row >> 2)) & 7);
}

__global__ __launch_bounds__(128, 2)
void k_cost(const float* __restrict__ Lf, const float* __restrict__ Rf, float* __restrict__ cv)
{
    __shared__ float4 Ls[TX * 8];   // 16 KB
    __shared__ float4 Rs[RR * 8];   // 22.5 KB
    const int t = threadIdx.x;
    const int xh = t & 31;
    const int dg = t >> 5;
    const int x0 = blockIdx.x * TX;
    const int h = blockIdx.y;
    const int b = blockIdx.z;
    const float* Lrow = Lf + (size_t)(b * HN + h) * WN * CN;
    const float* Rrow = Rf + (size_t)(b * HN + h) * WN * CN;
    const int d0 = dg * 13;
    const int rbase0 = 4 * xh + 36 - d0;   // R-row window base, in [-3, 160]

    float acc[13][4];
#pragma unroll
    for (int j = 0; j < 13; j++)
#pragma unroll
        for (int i = 0; i < 4; i++) acc[j][i] = 0.f;

#pragma unroll 1
    for (int c0 = 0; c0 < CN; c0 += KC) {
        __syncthreads();
        // stage L: 128 rows x 8 quads = 1024 -> 8 per thread
#pragma unroll
        for (int ii = 0; ii < 8; ii++) {
            int idx = t + ii * 128;
            int row = idx >> 3, q = idx & 7;
            int gx = x0 + row;
            float4 v = make_float4(0.f, 0.f, 0.f, 0.f);
            if (gx < WN) v = *(const float4*)(Lrow + (size_t)gx * CN + c0 + 4 * q);
            Ls[swz(row, q)] = v;
        }
        // stage R: 176 rows x 8 quads = 1408 -> 11 per thread
#pragma unroll
        for (int ii = 0; ii < 11; ii++) {
            int idx = t + ii * 128;
            int row = idx >> 3, q = idx & 7;
            int gx = x0 - 48 + row;
            float4 v = make_float4(0.f, 0.f, 0.f, 0.f);
            if (gx >= 0 && gx < WN) v = *(const float4*)(Rrow + (size_t)gx * CN + c0 + 4 * q);
            Rs[swz(row, q)] = v;
        }
        __syncthreads();

#pragma unroll
        for (int cq = 0; cq < 8; cq++) {
            float4 Lv[4];
#pragma unroll
            for (int i = 0; i < 4; i++) Lv[i] = Ls[swz(4 * xh + i, cq)];
            float4 Rv[16];
#pragma unroll
            for (int m = 0; m < 16; m++) {
                int row = rbase0 + m;
                row = row < 0 ? 0 : row;   // clamped rows feed only discarded outputs
                Rv[m] = Rs[swz(row, cq)];
            }
#pragma unroll
            for (int j = 0; j < 13; j++) {
#pragma unroll
                for (int i = 0; i < 4; i++) {
                    const float4 r = Rv[i - j + 12];
                    const float4 l = Lv[i];
                    acc[j][i] += l.x * r.x + l.y * r.y + l.z * r.z + l.w * r.w;
                }
            }
        }
    }

    const float NINF = -__builtin_inff();
    const int xq = x0 + 4 * xh;
    if (xq < WN) {   // WN%4==0 and xq%4==0 -> whole quad in-range
#pragma unroll
        for (int j = 0; j < 13; j++) {
            int d = d0 + j;
            if (d < D1) {
                float4 o;
                o.x = (xq + 0 >= d) ? acc[j][0] : NINF;
                o.y = (xq + 1 >= d) ? acc[j][1] : NINF;
                o.z = (xq + 2 >= d) ? acc[j][2] : NINF;
                o.w = (xq + 3 >= d) ? acc[j][3] : NINF;
                *(float4*)(cv + (size_t)(b * D1 + d) * HW + (size_t)h * WN + xq) = o;
            }
        }
    }
}

// ---------------- entropy (shared device fn) ----------------
__device__ __forceinline__ float entropy49(const float v[D1])
{
    float m = v[0];
#pragma unroll
    for (int d = 1; d < D1; d++) m = fmaxf(m, v[d]);
    float S = 0.f;
    int cnt = 0;
#pragma unroll
    for (int d = 0; d < D1; d++) {
        if (isfinite(v[d])) cnt++;
        S += expf((v[d] - m) * 10.0f);
    }
    float lS = logf(S);
    float e_acc = 0.f;
#pragma unroll
    for (int d = 0; d < D1; d++) {
        float l = (v[d] - m) * 10.0f;
        float pe = expf(l) / S;
        if (pe > 1e-8f) e_acc -= pe * (l - lS);
        else            e_acc += 1.8420681e-7f;  // -1e-8*ln(1e-8)
    }
    float out = 0.f;
    if (cnt > 1) out = e_acc / (logf((float)cnt) + 1e-8f);
    return fminf(fmaxf(out, 0.f), 1.f);
}

__global__ void k_entropy(const float* __restrict__ cv, float* __restrict__ ent)
{
    int p = blockIdx.x * 256 + threadIdx.x;   // grid = 468 exact
    int b = p / HW;
    int r = p - b * HW;
    const float* base = cv + (size_t)b * D1 * HW + r;
    float v[D1];
#pragma unroll
    for (int d = 0; d < D1; d++) v[d] = base[(size_t)d * HW];
    ent[p] = entropy49(v);
}

// ---------------- run extents + refine mask ----------------
// ROI (Python float semantics): rows [64,95], cols [62,218]
__global__ void k_extents(const float* __restrict__ ent, int* __restrict__ Aa,
                          int* __restrict__ Bb, unsigned char* __restrict__ rm)
{
    int row = blockIdx.x * 64 + threadIdx.x;
    if (row >= BN * HN) return;
    int h = row % HN;
    const float* er = ent + (size_t)row * WN;
    int* Ar = Aa + (size_t)row * WN;
    int* Br = Bb + (size_t)row * WN;
    unsigned char* mr = rm + (size_t)row * WN;
    const bool roi_row = (h >= 64 && h <= 95);

    int prev = -1;
    for (int x = 0; x < WN; x++) {
        bool val = er[x] <= 0.6f;
        if (val) prev = x;
        int L0 = x - prev - 1; if (L0 < 0) L0 = 0;
        int a = x - L0; if (a < 0) a = 0;
        int lo = x - 12; if (lo < 0) lo = 0;
        if (a < lo) a = lo;
        Ar[x] = a;
    }
    int nxt = WN;
    for (int x = WN - 1; x >= 0; x--) {
        bool val = er[x] <= 0.6f;
        if (val) nxt = x;
        int R0 = nxt - x - 1; if (R0 < 0) R0 = 0;
        int bb = x + R0; if (bb > WN - 1) bb = WN - 1;
        int hi = x + 12; if (hi > WN - 1) hi = WN - 1;
        if (bb > hi) bb = hi;
        Br[x] = bb;
        mr[x] = (!val && roi_row && x >= 62 && x <= 218) ? 1 : 0;
    }
}

// ---------------- fused refine + entropy (stage 1) ----------------
__global__ void k_refine_ent(const float* __restrict__ cvin, float* __restrict__ cvout,
                             const int* __restrict__ Aa, const int* __restrict__ Bb,
                             const unsigned char* __restrict__ rm, float* __restrict__ ent)
{
    int p = blockIdx.x * 256 + threadIdx.x;  // grid = 468 exact
    int b = p / HW;
    int r = p - b * HW;
    int h = r / WN;
    size_t colbase = (size_t)b * D1 * HW + r;
    float v[D1];
    if (!rm[p]) {
#pragma unroll
        for (int d = 0; d < D1; d++) v[d] = cvin[colbase + (size_t)d * HW];
    } else {
        int a = Aa[p], bb = Bb[p];
        size_t rowb = (size_t)b * D1 * HW + (size_t)h * WN;
        for (int d = 0; d < D1; d++) {
            const float* rp = cvin + rowb + (size_t)d * HW;
            float num = 0.f; int den = 0;
            for (int xx = a; xx <= bb; xx++) {
                float w = rp[xx];
                if (isfinite(w)) { num += w; den++; }
            }
            v[d] = (den > 0) ? num / (float)den : -__builtin_inff();
        }
    }
    ent[p] = entropy49(v);
#pragma unroll
    for (int d = 0; d < D1; d++) cvout[colbase + (size_t)d * HW] = v[d];
}

// ---------------- fused refine (stage 2) + argmax + loss ----------------
__global__ void k_refine_loss(const float* __restrict__ cvin, const int* __restrict__ Aa,
                              const int* __restrict__ Bb, const unsigned char* __restrict__ rm,
                              const float* __restrict__ student, float* __restrict__ accum)
{
    int p = blockIdx.x * 256 + threadIdx.x;  // grid = 468
    int b = p / HW;
    int r = p - b * HW;
    int h = r / WN;
    float sl1 = 0.f, msk = 0.f;
    if (rm[p]) {
        int a = Aa[p], bb = Bb[p];
        size_t rowb = (size_t)b * D1 * HW + (size_t)h * WN;
        float best = -__builtin_inff();
        int bi = 0;
        for (int d = 0; d < D1; d++) {
            const float* rp = cvin + rowb + (size_t)d * HW;
            float num = 0.f; int den = 0;
            for (int xx = a; xx <= bb; xx++) {
                float w = rp[xx];
                if (isfinite(w)) { num += w; den++; }
            }
            float agg = (den > 0) ? num / (float)den : -__builtin_inff();
            if (agg > best) { best = agg; bi = d; }   // first-max tie-break
        }
        float diff = student[p] * 0.25f - (float)bi;
        float ad = fabsf(diff);
        sl1 = (ad < 1.f) ? 0.5f * ad * ad : ad - 0.5f;
        msk = 1.f;
    }
#pragma unroll
    for (int off = 32; off; off >>= 1) {
        sl1 += __shfl_down(sl1, off);
        msk += __shfl_down(msk, off);
    }
    __shared__ float s1[4], s2[4];
    int w = threadIdx.x >> 6, lane = threadIdx.x & 63;
    if (lane == 0) { s1[w] = sl1; s2[w] = msk; }
    __syncthreads();
    if (threadIdx.x == 0) {
        float aa = s1[0] + s1[1] + s1[2] + s1[3];
        float cc = s2[0] + s2[1] + s2[2] + s2[3];
        atomicAdd(&accum[b * 2], aa);
        atomicAdd(&accum[b * 2 + 1], cc);
    }
}

__global__ void k_finalize(const float* __restrict__ accum, float* __restrict__ out)
{
    if (threadIdx.x == 0 && blockIdx.x == 0) {
        float s = 0.f;
        for (int b = 0; b < BN; b++) {
            float c = accum[2 * b + 1];
            if (c < 1.f) c = 1.f;
            s += accum[2 * b] / c;
        }
        out[0] = s * 0.25f;
    }
}

extern "C" void kernel_launch(void* const* d_in, const int* in_sizes, int n_in,
                              void* d_out, int out_size, void* d_ws, size_t ws_size,
                              hipStream_t stream)
{
    const float* fL = (const float*)d_in[0];
    const float* fR = (const float*)d_in[1];
    const float* st = (const float*)d_in[2];
    float* out = (float*)d_out;

    float* cv0 = (float*)d_ws;
    float* cv1 = cv0 + CVSZ;
    float* ent = cv1 + CVSZ;
    int* Aa = (int*)(ent + NPIX);
    int* Bb = Aa + NPIX;
    unsigned char* rm = (unsigned char*)(Bb + NPIX);
    float* accum = (float*)(rm + NPIX);   // NPIX is 16B-aligned count

    // E0
    k_cost<<<dim3(3, 96, 4), 128, 0, stream>>>(fL, fR, cv0);
    // ent0
    k_entropy<<<dim3(NPIX / 256), 256, 0, stream>>>(cv0, ent);
    // extents1 + rm1
    k_extents<<<dim3(6), 64, 0, stream>>>(ent, Aa, Bb, rm);
    // E1 + ent1 (fused)
    k_refine_ent<<<dim3(NPIX / 256), 256, 0, stream>>>(cv0, cv1, Aa, Bb, rm, ent);
    // extents2 + rm2
    k_extents<<<dim3(6), 64, 0, stream>>>(ent, Aa, Bb, rm);
    // E2 + argmax + loss (fused, E2 never materialized)
    hipMemsetAsync(accum, 0, 8 * sizeof(float), stream);
    k_refine_loss<<<dim3(NPIX / 256), 256, 0, stream>>>(cv1, Aa, Bb, rm, st, accum);
    k_finalize<<<1, 64, 0, stream>>>(accum, out);
}